// Round 1
// baseline (116.950 us; speedup 1.0000x reference)
//
#include <hip/hip_runtime.h>
#include <stdint.h>

#define BSZ 8
#define GQ 2000
#define NPTS (BSZ * GQ)
#define CH 128            // C_IN == C_OUT == 128
#define KOFF 125          // 5^3 offsets
#define TBL_BITS 16
#define TBL_SIZE (1 << TBL_BITS)
#define TBL_MASK (TBL_SIZE - 1)

struct Slot { int key; int val; };

__device__ __forceinline__ uint32_t hash_of(uint32_t k) {
    return (k * 2654435761u) >> (32 - TBL_BITS);
}

// Exact replication of the reference's fp32 voxel-index arithmetic:
//   xyz = a * s + lo   (mul, then add, separately rounded — no FMA)
//   q   = (xyz - lo) / 0.1f
//   idx = trunc(q)
__device__ __forceinline__ int3 voxel_idx(const float* __restrict__ anchor, int i,
                                          float sx, float sy, float sz,
                                          float lx, float ly, float lz, float g) {
    float ax = anchor[i * 3 + 0];
    float ay = anchor[i * 3 + 1];
    float az = anchor[i * 3 + 2];
    float x = __fadd_rn(__fmul_rn(ax, sx), lx);
    float y = __fadd_rn(__fmul_rn(ay, sy), ly);
    float z = __fadd_rn(__fmul_rn(az, sz), lz);
    int ix = (int)__fdiv_rn(__fsub_rn(x, lx), g);
    int iy = (int)__fdiv_rn(__fsub_rn(y, ly), g);
    int iz = (int)__fdiv_rn(__fsub_rn(z, lz), g);
    return make_int3(ix, iy, iz);
}

__global__ void build_hash_kernel(const float* __restrict__ anchor,
                                  Slot* __restrict__ tab,
                                  float sx, float sy, float sz,
                                  float lx, float ly, float lz, float g,
                                  int Dx, int Dy, int Dz) {
    int i = blockIdx.x * blockDim.x + threadIdx.x;
    if (i >= NPTS) return;
    int3 v = voxel_idx(anchor, i, sx, sy, sz, lx, ly, lz, g);
    // OOB scatter updates are dropped (JAX default scatter mode)
    if (v.x < 0 || v.x >= Dx || v.y < 0 || v.y >= Dy || v.z < 0 || v.z >= Dz) return;
    int b = i / GQ;
    int key = ((b * Dx + v.x) * Dy + v.y) * Dz + v.z;   // < 8*400*400*31 = 39.7M
    uint32_t slot = hash_of((uint32_t)key);
    for (;;) {
        int prev = atomicCAS(&tab[slot].key, -1, key);
        if (prev == -1 || prev == key) {
            atomicMax(&tab[slot].val, i);   // duplicate voxel: max index == last write wins
            break;
        }
        slot = (slot + 1) & TBL_MASK;
    }
}

__device__ __forceinline__ int hash_query(const Slot* __restrict__ tab, int key) {
    uint32_t slot = hash_of((uint32_t)key);
    for (;;) {
        int k = tab[slot].key;
        if (k == key) return tab[slot].val;
        if (k == -1) return -1;
        slot = (slot + 1) & TBL_MASK;
    }
}

// One block (128 threads) per output point. Phase 1: 125 threads probe the
// hash for the 5^3 neighborhood, compact hits into LDS. Phase 2: for each hit,
// stage feats[j] into LDS, every thread accumulates one c_out column of w[k].
__global__ void __launch_bounds__(CH)
sconv_kernel(const float* __restrict__ feat,
             const float* __restrict__ anchor,
             const float* __restrict__ w,
             const Slot* __restrict__ tab,
             float* __restrict__ out,
             float sx, float sy, float sz,
             float lx, float ly, float lz, float g,
             int Dx, int Dy, int Dz) {
    __shared__ int cnt;
    __shared__ int lk[KOFF];
    __shared__ int lj[KOFF];
    __shared__ float fbuf[CH];

    int i = blockIdx.x;
    int t = threadIdx.x;
    if (t == 0) cnt = 0;
    __syncthreads();

    int3 v = voxel_idx(anchor, i, sx, sy, sz, lx, ly, lz, g);
    int b = i / GQ;

    if (t < KOFF) {
        int ox = t / 25 - 2;
        int oy = (t / 5) % 5 - 2;
        int oz = t % 5 - 2;
        int nx = v.x + ox, ny = v.y + oy, nz = v.z + oz;
        if (nx >= 0 && nx < Dx && ny >= 0 && ny < Dy && nz >= 0 && nz < Dz) {
            int key = ((b * Dx + nx) * Dy + ny) * Dz + nz;
            int j = hash_query(tab, key);
            if (j >= 0) {
                int p = atomicAdd(&cnt, 1);
                lk[p] = t;
                lj[p] = j;
            }
        }
    }
    __syncthreads();

    float acc = 0.0f;
    int m = cnt;
    for (int q = 0; q < m; ++q) {
        int j = lj[q];
        int k = lk[q];
        __syncthreads();                 // protect fbuf from previous iteration's readers
        fbuf[t] = feat[j * CH + t];
        __syncthreads();
        const float* wk = w + k * CH * CH + t;   // column t of w[k], stride CH
        #pragma unroll 16
        for (int ci = 0; ci < CH; ++ci) {
            acc = fmaf(fbuf[ci], wk[ci * CH], acc);
        }
    }
    out[i * CH + t] = acc;
}

extern "C" void kernel_launch(void* const* d_in, const int* in_sizes, int n_in,
                              void* d_out, int out_size, void* d_ws, size_t ws_size,
                              hipStream_t stream) {
    const float* feat   = (const float*)d_in[0];   // (8, 2000, 128)
    const float* anchor = (const float*)d_in[1];   // (8, 2000, 3)
    const float* w      = (const float*)d_in[2];   // (125, 128, 128)
    float* out = (float*)d_out;
    Slot* tab = (Slot*)d_ws;                       // 512 KB hash table

    // key = val = -1 sentinel
    hipMemsetAsync(d_ws, 0xFF, (size_t)TBL_SIZE * sizeof(Slot), stream);

    // fp32 constants exactly as the reference computes them
    float lx = -20.0f, ly = -20.0f, lz = -2.3f;
    float hx =  20.0f, hy =  20.0f, hz =  0.9f;
    float sx = hx - lx, sy = hy - ly, sz = hz - lz;   // sz -> 3.19999980926514f
    float g = 0.1f;
    int Dx = (int)(sx / g);   // 400
    int Dy = (int)(sy / g);   // 400
    int Dz = (int)(sz / g);   // 31  (31.9999981 truncated)

    build_hash_kernel<<<(NPTS + 255) / 256, 256, 0, stream>>>(
        anchor, tab, sx, sy, sz, lx, ly, lz, g, Dx, Dy, Dz);

    sconv_kernel<<<NPTS, CH, 0, stream>>>(
        feat, anchor, w, tab, out, sx, sy, sz, lx, ly, lz, g, Dx, Dy, Dz);
}